// Round 5
// baseline (271.854 us; speedup 1.0000x reference)
//
#include <hip/hip_runtime.h>

// MSD via MFMA. R12: K-split x8 -> LDS 25.6 KB -> 6 blocks/CU (was 3).
// msd[td] = (1/(180*1536)) * sum_i ( S[t] + S[100i] - 2*<x[t],x[100i]> ), t=100i+td
//
// R11 post-mortem: total 192.6 = ~141 harness poison-fills (2x 480MB @71us,
// immovable) + dot ~47 + reduce ~4. Dot runs at ~2.6 TB/s effective fetch --
// latency-bound at 3 blocks/CU (50 KB LDS, 37.5% occ), not HBM-bound.
// Fix: halve tile K-extent (NKC=8, KC=192, NKS=6). Bytes/MFMA/VALU all
// unchanged; LDS 25.6 KB -> 6 blocks/CU = 24 waves/CU. LROW=200 shorts keeps
// <=2-way LDS banking (row stride 100 words == 4 mod 32). Round-robin XCD
// dispatch puts all blocks of a kc-plane on one XCD (bid%8==kc) -> origin
// B-rows (138 KB/plane) stay L2-resident per XCD.
// S fused into A staging as before (f32 before bf16 pack); 8 plane-partials.
// ws: 8 dot planes [kc][i][td] (11.52 MB) + 8 S planes [kc][t] (640 KB).
// bf16 cross term only (absmax 7.8e-3 << 4e-2, stable R6-R11).

typedef __attribute__((ext_vector_type(8))) short bf16x8;
typedef __attribute__((ext_vector_type(4))) short bf16x4;
typedef __attribute__((ext_vector_type(4))) float f32x4;

#define ROWF   1536
#define NFRAME 20000
#define NORIG  180
#define WIN    20
#define FB     32
#define NFB    625      // 625*32 = 20000 exactly
#define NKC    8        // K planes
#define KC     192      // 1536 / 8
#define NKS    6        // 192 / 32
#define TDMAX  2000
#define PLANE  (NORIG * TDMAX)          // 360000 floats per K-plane
#define SOFF   (NKC * PLANE)            // S planes live after the dot planes
#define LROW   200                      // 192 bf16 + 8 pad -> 400B row stride
#define SCALE  (1.0f / (1536.0f * 180.0f))

static __device__ __forceinline__ short f2bf(float f) {
    unsigned u = __builtin_bit_cast(unsigned, f);
    u += 0x7fffu + ((u >> 16) & 1u);
    return (short)(u >> 16);
}

static __device__ __forceinline__ bf16x4 pack4(const float4& v) {
    bf16x4 r;
    r[0] = f2bf(v.x); r[1] = f2bf(v.y); r[2] = f2bf(v.z); r[3] = f2bf(v.w);
    return r;
}

__global__ __launch_bounds__(256)
void msd_dot_kernel(const float* __restrict__ x, float* __restrict__ ws) {
    __shared__ short lA[FB * LROW];   // 12800 B
    __shared__ short lB[FB * LROW];   // 12800 B

    const int fb  = blockIdx.x >> 3;    // frame block
    const int kc  = blockIdx.x & 7;     // K plane
    const int t0  = fb * FB;
    const int tid = threadIdx.x;

    const int cmin = t0 / 100;
    int iBase = cmin - (WIN - 1); if (iBase < 0) iBase = 0;

    // ---- stage A (row-grouped) + inline f32 sumsq ----
    // 32 rows x 48 float4; thread (r = tid>>3, c8 = tid&7) loads 6 float4s
    // of row r at columns c8 + 8*it. Wave = 8 rows x 128B contiguous segments.
    {
        const int r  = tid >> 3;
        const int c8 = tid & 7;
        const float* src = x + (size_t)(t0 + r) * ROWF + kc * KC + c8 * 4;
        short* dst = &lA[r * LROW + c8 * 4];
        float sq = 0.0f;
        #pragma unroll
        for (int it = 0; it < 6; ++it) {
            const float4 v = *(const float4*)(src + it * 32);
            sq += v.x*v.x + v.y*v.y + v.z*v.z + v.w*v.w;
            *(bf16x4*)(dst + it * 32) = pack4(v);
        }
        sq += __shfl_xor(sq, 1, 64);
        sq += __shfl_xor(sq, 2, 64);
        sq += __shfl_xor(sq, 4, 64);
        if (c8 == 0)
            ws[SOFF + (size_t)kc * NFRAME + t0 + r] = sq;   // plane-partial S
    }
    // ---- stage B: 32 origin rows (clamped), same mapping, no S needed ----
    {
        const int r  = tid >> 3;
        const int c8 = tid & 7;
        const int iNom = iBase + r;
        const int iClp = (iNom < NORIG) ? iNom : (NORIG - 1);
        const float* src = x + (size_t)(iClp * 100) * ROWF + kc * KC + c8 * 4;
        short* dst = &lB[r * LROW + c8 * 4];
        #pragma unroll
        for (int it = 0; it < 6; ++it) {
            const float4 v = *(const float4*)(src + it * 32);
            *(bf16x4*)(dst + it * 32) = pack4(v);
        }
    }
    __syncthreads();

    // ---- MFMA from LDS ----
    const int lane = tid & 63;
    const int w    = tid >> 6;   // 4 waves
    const int mt   = w >> 1;     // frame half (16 frames)
    const int nt   = w & 1;      // origin half (16 slots)
    const int m    = lane & 15;
    const int quad = lane >> 4;

    const short* pa = &lA[(16 * mt + m) * LROW + quad * 8];
    const short* pb = &lB[(16 * nt + m) * LROW + quad * 8];

    f32x4 acc = {};
    #pragma unroll
    for (int ks = 0; ks < NKS; ++ks) {
        acc = __builtin_amdgcn_mfma_f32_16x16x32_bf16(*(const bf16x8*)(pa + ks * 32),
                                                      *(const bf16x8*)(pb + ks * 32),
                                                      acc, 0, 0, 0);
    }

    // C/D layout: col = lane&15 (origin slot), row = quad*4 + r (frame-in-tile).
    // Store raw dot plane-partial into [kc][i][td]; each valid (i,td) is
    // produced by exactly one frame-block (t = 100i+td), no collisions.
    float* wsp = ws + (size_t)kc * PLANE;
    #pragma unroll
    for (int r = 0; r < 4; ++r) {
        const int j  = 16 * mt + quad * 4 + r;     // frame within block
        const int tt = t0 + j;
        const int c  = tt / 100;
        const int i  = iBase + 16 * nt + m;        // nominal origin of this col
        const int k  = c - i;
        if (k >= 0 && k < WIN && i < NORIG) {
            const int td = tt - 100 * i;           // in [0, 2000)
            wsp[(size_t)i * TDMAX + td] = acc[r];
        }
    }
}

// out[td] = SCALE * sum_i ( S[100i+td] + S[100i] - 2 * sum_kc dot[kc][i][td] )
// S[t] = sum_kc Spl[kc][t]. 32 blocks x 256: lane = td within a 64-td chunk,
// wave w covers i in [45w, 45w+45).
__global__ __launch_bounds__(256)
void msd_reduce_kernel(const float* __restrict__ ws, float* __restrict__ out) {
    __shared__ float red[4][64];
    const int lane = threadIdx.x & 63;
    const int w    = threadIdx.x >> 6;
    const int td   = blockIdx.x * 64 + lane;
    const int tdc  = (td < TDMAX) ? td : (TDMAX - 1);   // clamp, no OOB
    const float* Sp = ws + SOFF;

    float acc = 0.0f;
    #pragma unroll 3
    for (int i = w * 45; i < w * 45 + 45; ++i) {
        const int t = 100 * i + tdc;
        float St = 0.0f, Si = 0.0f, d = 0.0f;
        #pragma unroll
        for (int kcp = 0; kcp < NKC; ++kcp) {
            St += Sp[(size_t)kcp * NFRAME + t];
            Si += Sp[(size_t)kcp * NFRAME + 100 * i];
            d  += ws[(size_t)kcp * PLANE + (size_t)i * TDMAX + tdc];
        }
        acc += St + Si - 2.0f * d;
    }
    red[w][lane] = acc;
    __syncthreads();
    if (w == 0 && td < TDMAX)
        out[td] = (red[0][lane] + red[1][lane] + red[2][lane] + red[3][lane]) * SCALE;
}

extern "C" void kernel_launch(void* const* d_in, const int* in_sizes, int n_in,
                              void* d_out, int out_size, void* d_ws, size_t ws_size,
                              hipStream_t stream) {
    const float* x = (const float*)d_in[0];
    float* out = (float*)d_out;
    float* ws  = (float*)d_ws;    // needs (8*360000 + 8*20000)*4 = 12.16 MB

    msd_dot_kernel<<<NFB * NKC, 256, 0, stream>>>(x, ws);
    msd_reduce_kernel<<<(TDMAX + 63) / 64, 256, 0, stream>>>(ws, out);
}

// Round 6
// 181.512 us; speedup vs baseline: 1.4977x; 1.4977x over previous
//
#include <hip/hip_runtime.h>

// MSD via MFMA. R13: keep R12 dot kernel (31 us, occupancy fix verified);
// fix the reduce that R12 broke (99 us) with a two-stage wide-grid reduce.
// msd[td] = (1/(180*1536)) * sum_i ( S[t] + S[100i] - 2*<x[t],x[100i]> ), t=100i+td
//
// R12 post-mortem: dot 47->31 us (K-split x8, 6 blocks/CU) as predicted, but
// reduce went 7->99 us: 32 blocks (128 waves, occ 1.3%), 1080 scalar loads
// per thread, VGPR 24 -> ~4 outstanding -> pure LLC/HBM latency chain.
// Fix: stage1 = 256 blocks (32 td-chunks x 8 i-chunks), 4 waves interleave
// the ~23 origins of the chunk -> ~144 loads/thread, 1024 waves; all loads
// coalesced (d, St) or broadcast (Si); LDS combine -> part[iChunk][td].
// stage2 = 8 blocks: out[td] = SCALE * sum_j part[j][td], coalesced.
// ws: 8 dot planes [kc][i][td] (11.52 MB) + 8 S planes [kc][t] (640 KB)
//     + part [8][2000] (64 KB) = 12.23 MB.
// bf16 cross term only (absmax 7.8e-3 << 4e-2, stable R6-R12).

typedef __attribute__((ext_vector_type(8))) short bf16x8;
typedef __attribute__((ext_vector_type(4))) short bf16x4;
typedef __attribute__((ext_vector_type(4))) float f32x4;

#define ROWF   1536
#define NFRAME 20000
#define NORIG  180
#define WIN    20
#define FB     32
#define NFB    625      // 625*32 = 20000 exactly
#define NKC    8        // K planes
#define KC     192      // 1536 / 8
#define NKS    6        // 192 / 32
#define TDMAX  2000
#define PLANE  (NORIG * TDMAX)          // 360000 floats per K-plane
#define SOFF   (NKC * PLANE)            // S planes after dot planes
#define POFF   (SOFF + NKC * NFRAME)    // stage-1 partials after S planes
#define LROW   200                      // 192 bf16 + 8 pad -> 400B row stride
#define SCALE  (1.0f / (1536.0f * 180.0f))

static __device__ __forceinline__ short f2bf(float f) {
    unsigned u = __builtin_bit_cast(unsigned, f);
    u += 0x7fffu + ((u >> 16) & 1u);
    return (short)(u >> 16);
}

static __device__ __forceinline__ bf16x4 pack4(const float4& v) {
    bf16x4 r;
    r[0] = f2bf(v.x); r[1] = f2bf(v.y); r[2] = f2bf(v.z); r[3] = f2bf(v.w);
    return r;
}

__global__ __launch_bounds__(256)
void msd_dot_kernel(const float* __restrict__ x, float* __restrict__ ws) {
    __shared__ short lA[FB * LROW];   // 12800 B
    __shared__ short lB[FB * LROW];   // 12800 B

    const int fb  = blockIdx.x >> 3;    // frame block
    const int kc  = blockIdx.x & 7;     // K plane
    const int t0  = fb * FB;
    const int tid = threadIdx.x;

    const int cmin = t0 / 100;
    int iBase = cmin - (WIN - 1); if (iBase < 0) iBase = 0;

    // ---- stage A (row-grouped) + inline f32 sumsq ----
    {
        const int r  = tid >> 3;
        const int c8 = tid & 7;
        const float* src = x + (size_t)(t0 + r) * ROWF + kc * KC + c8 * 4;
        short* dst = &lA[r * LROW + c8 * 4];
        float sq = 0.0f;
        #pragma unroll
        for (int it = 0; it < 6; ++it) {
            const float4 v = *(const float4*)(src + it * 32);
            sq += v.x*v.x + v.y*v.y + v.z*v.z + v.w*v.w;
            *(bf16x4*)(dst + it * 32) = pack4(v);
        }
        sq += __shfl_xor(sq, 1, 64);
        sq += __shfl_xor(sq, 2, 64);
        sq += __shfl_xor(sq, 4, 64);
        if (c8 == 0)
            ws[SOFF + (size_t)kc * NFRAME + t0 + r] = sq;   // plane-partial S
    }
    // ---- stage B: 32 origin rows (clamped), same mapping ----
    {
        const int r  = tid >> 3;
        const int c8 = tid & 7;
        const int iNom = iBase + r;
        const int iClp = (iNom < NORIG) ? iNom : (NORIG - 1);
        const float* src = x + (size_t)(iClp * 100) * ROWF + kc * KC + c8 * 4;
        short* dst = &lB[r * LROW + c8 * 4];
        #pragma unroll
        for (int it = 0; it < 6; ++it) {
            const float4 v = *(const float4*)(src + it * 32);
            *(bf16x4*)(dst + it * 32) = pack4(v);
        }
    }
    __syncthreads();

    // ---- MFMA from LDS ----
    const int lane = tid & 63;
    const int w    = tid >> 6;   // 4 waves
    const int mt   = w >> 1;     // frame half (16 frames)
    const int nt   = w & 1;      // origin half (16 slots)
    const int m    = lane & 15;
    const int quad = lane >> 4;

    const short* pa = &lA[(16 * mt + m) * LROW + quad * 8];
    const short* pb = &lB[(16 * nt + m) * LROW + quad * 8];

    f32x4 acc = {};
    #pragma unroll
    for (int ks = 0; ks < NKS; ++ks) {
        acc = __builtin_amdgcn_mfma_f32_16x16x32_bf16(*(const bf16x8*)(pa + ks * 32),
                                                      *(const bf16x8*)(pb + ks * 32),
                                                      acc, 0, 0, 0);
    }

    // C/D layout: col = lane&15 (origin slot), row = quad*4 + r (frame-in-tile).
    float* wsp = ws + (size_t)kc * PLANE;
    #pragma unroll
    for (int r = 0; r < 4; ++r) {
        const int j  = 16 * mt + quad * 4 + r;     // frame within block
        const int tt = t0 + j;
        const int c  = tt / 100;
        const int i  = iBase + 16 * nt + m;        // nominal origin of this col
        const int k  = c - i;
        if (k >= 0 && k < WIN && i < NORIG) {
            const int td = tt - 100 * i;           // in [0, 2000)
            wsp[(size_t)i * TDMAX + td] = acc[r];
        }
    }
}

// Stage 1: 256 blocks = (32 td-chunks) x (8 i-chunks). Lanes = consecutive td.
// part[iChunk][td] = sum over the chunk's origins of (S[t]+S[100i]-2*dot).
__global__ __launch_bounds__(256)
void msd_reduce1_kernel(const float* __restrict__ ws, float* __restrict__ part) {
    __shared__ float red[4][64];
    const int bx      = blockIdx.x;
    const int tdChunk = bx >> 3;
    const int iChunk  = bx & 7;
    const int lane = threadIdx.x & 63;
    const int w    = threadIdx.x >> 6;
    const int td   = tdChunk * 64 + lane;
    const int tdc  = (td < TDMAX) ? td : (TDMAX - 1);   // clamp, no OOB
    const float* Sp = ws + SOFF;

    const int i0 = iChunk * 23;
    const int i1 = (i0 + 23 < NORIG) ? (i0 + 23) : NORIG;

    float acc = 0.0f;
    for (int i = i0 + w; i < i1; i += 4) {       // ~6 iters per thread
        const int t = 100 * i + tdc;
        float St = 0.0f, Si = 0.0f, D = 0.0f;
        #pragma unroll
        for (int kcp = 0; kcp < NKC; ++kcp) {
            St += Sp[(size_t)kcp * NFRAME + t];            // coalesced
            Si += Sp[(size_t)kcp * NFRAME + 100 * i];      // broadcast
            D  += ws[(size_t)kcp * PLANE + (size_t)i * TDMAX + tdc];  // coalesced
        }
        acc += St + Si - 2.0f * D;
    }
    red[w][lane] = acc;
    __syncthreads();
    if (w == 0 && td < TDMAX)
        part[(size_t)iChunk * TDMAX + td] =
            red[0][lane] + red[1][lane] + red[2][lane] + red[3][lane];
}

// Stage 2: out[td] = SCALE * sum_j part[j][td]. 8 blocks x 256, coalesced.
__global__ __launch_bounds__(256)
void msd_reduce2_kernel(const float* __restrict__ part, float* __restrict__ out) {
    const int td = blockIdx.x * 256 + threadIdx.x;
    if (td >= TDMAX) return;
    float a = 0.0f;
    #pragma unroll
    for (int j = 0; j < 8; ++j)
        a += part[(size_t)j * TDMAX + td];
    out[td] = a * SCALE;
}

extern "C" void kernel_launch(void* const* d_in, const int* in_sizes, int n_in,
                              void* d_out, int out_size, void* d_ws, size_t ws_size,
                              hipStream_t stream) {
    const float* x = (const float*)d_in[0];
    float* out = (float*)d_out;
    float* ws  = (float*)d_ws;    // needs (POFF + 8*2000)*4 = 12.23 MB

    msd_dot_kernel<<<NFB * NKC, 256, 0, stream>>>(x, ws);
    msd_reduce1_kernel<<<256, 256, 0, stream>>>(ws, ws + POFF);
    msd_reduce2_kernel<<<8, 256, 0, stream>>>(ws + POFF, out);
}